// Round 7
// baseline (248.636 us; speedup 1.0000x reference)
//
#include <hip/hip_runtime.h>
#include <hip/hip_bf16.h>
#include <stdint.h>

#define B_  2
#define S_  4096
#define D_  768
#define H_  12
#define DH_ 64
#define BS_ (B_*S_)   // 8192

typedef __bf16 bf16x8 __attribute__((ext_vector_type(8)));
typedef short  svec8  __attribute__((ext_vector_type(8)));
typedef float  fvec4  __attribute__((ext_vector_type(4)));
typedef int    ivec4  __attribute__((ext_vector_type(4)));
typedef unsigned short ushort_t;

// native RNE float->bf16
__device__ __forceinline__ ushort_t bfc(float f){
    return __builtin_bit_cast(ushort_t, (__bf16)f);
}

__device__ __forceinline__ unsigned cvt_pk_bf16(float lo, float hi){
    unsigned r;
    asm("v_cvt_pk_bf16_f32 %0, %1, %2" : "=v"(r) : "v"(lo), "v"(hi));
    return r;   // low16 = bf16(lo), high16 = bf16(hi)
}

__device__ __forceinline__ fvec4 mfma16(svec8 a, svec8 b, fvec4 c){
    return __builtin_amdgcn_mfma_f32_16x16x32_bf16(
        __builtin_bit_cast(bf16x8, a), __builtin_bit_cast(bf16x8, b), c, 0, 0, 0);
}

// ---------------- prep: one-shot convert + fragment-swizzle (R15) ----------------
// R15 fix: R13/R14's W pass SCATTERED 2B stores at 64B stride (1.77M of them) --
// likely tens of us of hidden time. Inverted to a GATHER: each thread owns one
// contiguous 16B dst chunk and gathers its 8 source floats. Map identical to R14:
//   addr(k,n) = ((k>>5)*4 + (n>>4))*512 + (n&15)*32 + ((k>>3)&3)*8 + (k&7)
// decomposes as a = [k5][nblk][n&15][q2][j]: thread chunk a -> n fixed, k = k0+j.
__global__ __launch_bounds__(256) void prep(
    const float* __restrict__ X,
    const float* __restrict__ Wq, const float* __restrict__ Wk, const float* __restrict__ Wv,
    ushort_t* __restrict__ Xb, ushort_t* __restrict__ Wsz)
{
    const int bid = blockIdx.x;
    if (bid < 3072) {
        size_t idx = ((size_t)bid * 256 + threadIdx.x) * 8;
        float4 d0 = *(const float4*)(X + idx);
        float4 d1 = *(const float4*)(X + idx + 4);
        bf16x8 pk;
        pk[0] = (__bf16)d0.x; pk[1] = (__bf16)d0.y;
        pk[2] = (__bf16)d0.z; pk[3] = (__bf16)d0.w;
        pk[4] = (__bf16)d1.x; pk[5] = (__bf16)d1.y;
        pk[6] = (__bf16)d1.z; pk[7] = (__bf16)d1.w;
        *(svec8*)(Xb + idx) = __builtin_bit_cast(svec8, pk);
    } else {
        const int v  = bid - 3072;        // 0..431
        const int wt = v % 3;
        const int hk = v / 3;             // h*12 + kt
        const int h  = hk / 12, kt = hk % 12;
        const float* W  = (wt == 0) ? Wq : (wt == 1) ? Wk : Wv;
        const float* Wh = W + (size_t)h * (D_ * DH_) + (size_t)kt * 64 * DH_;
        ushort_t* dst = Wsz + (size_t)(hk * 3 + wt) * 4096;
        #pragma unroll
        for (int i = 0; i < 2; i++) {
            int a    = (threadIdx.x + 256 * i) * 8;   // dst u16 base in [0,4096)
            int k5   = a >> 11;
            int nblk = (a >> 9) & 3;
            int n    = nblk * 16 + ((a >> 5) & 15);
            int q2   = (a >> 3) & 3;
            int k0   = k5 * 32 + q2 * 8;
            bf16x8 pk;
            #pragma unroll
            for (int j = 0; j < 8; j++) pk[j] = (__bf16)Wh[(k0 + j) * DH_ + n];
            *(svec8*)(dst + a) = __builtin_bit_cast(svec8, pk);
        }
    }
}

// ---------------- fused QKV projection (R14 kernel, verbatim) ----------------
__global__ __launch_bounds__(256, 3) void qkv_proj(
    const ushort_t* __restrict__ Xb, const ushort_t* __restrict__ Wsz,
    ushort_t* __restrict__ Qb, ushort_t* __restrict__ Kb, ushort_t* __restrict__ Vg)
{
    const int m0 = blockIdx.x * 128;
    const int h  = blockIdx.y;

    __shared__ ushort_t smem[128 * 64 + 3 * 4096];   // 40960 B
    ushort_t* Xs  = smem;              // X tile, fragment-linear
    ushort_t* Wts = smem + 128 * 64;   // 3 W panels, fragment-linear
    ushort_t* XsT = smem;              // 64 x 136 overlay, used after K-loop

    const int tid  = threadIdx.x;
    const int w    = tid >> 6;
    const int lane = tid & 63;
    const int quad = lane >> 4;
    const int l15  = lane & 15;
    const int lp8  = (l15 * 4 + quad) * 8;   // lane fragment offset (ushorts)

    fvec4 acc[3][2][4];
    #pragma unroll
    for (int wt = 0; wt < 3; wt++)
        #pragma unroll
        for (int i = 0; i < 2; i++)
            #pragma unroll
            for (int j = 0; j < 4; j++) acc[wt][i][j] = (fvec4){0.f, 0.f, 0.f, 0.f};

    const ushort_t* xsrc = Xb + (size_t)m0 * D_;
    const ushort_t* wsrc = Wsz + (size_t)(h * 12) * 3 * 4096;

    int xr[4], xdu[4];
    #pragma unroll
    for (int i = 0; i < 4; i++) {
        int v = tid + 256 * i;
        int r = v >> 3, t = v & 7;
        xr[i]  = r * D_ + t * 8;
        xdu[i] = (((r >> 4) * 2 + (t >> 2)) * 64 + (r & 15) * 4 + (t & 3)) * 8;
    }

    svec8 xd[4];
    #pragma unroll
    for (int i = 0; i < 4; i++) xd[i] = *(const svec8*)(xsrc + xr[i]);

    for (int kt = 0; kt < 12; kt++) {
        const ushort_t* wp = wsrc + (size_t)kt * 3 * 4096;
        svec8 wd[6];
        #pragma unroll
        for (int j = 0; j < 6; j++)
            wd[j] = *(const svec8*)(wp + (tid + 256 * j) * 8);
        #pragma unroll
        for (int i = 0; i < 4; i++) *(svec8*)(Xs + xdu[i]) = xd[i];
        #pragma unroll
        for (int j = 0; j < 6; j++) *(svec8*)(Wts + (tid + 256 * j) * 8) = wd[j];
        __syncthreads();

        if (kt < 11) {
            #pragma unroll
            for (int i = 0; i < 4; i++)
                xd[i] = *(const svec8*)(xsrc + xr[i] + (kt + 1) * 64);
        }

        #pragma unroll
        for (int ks = 0; ks < 2; ks++) {
            svec8 a0 = *(const svec8*)(Xs + (4 * w + ks) * 512 + lp8);
            svec8 a1 = *(const svec8*)(Xs + (4 * w + 2 + ks) * 512 + lp8);
            #pragma unroll
            for (int wt = 0; wt < 3; wt++)
                #pragma unroll
                for (int ns = 0; ns < 4; ns++) {
                    svec8 b = *(const svec8*)(Wts + (wt * 8 + ks * 4 + ns) * 512 + lp8);
                    acc[wt][0][ns] = mfma16(a0, b, acc[wt][0][ns]);
                    acc[wt][1][ns] = mfma16(a1, b, acc[wt][1][ns]);
                }
        }
        __syncthreads();
    }

    const float qs = 0.18033688011112042f;   // 1/8 * log2(e)
    #pragma unroll
    for (int ms = 0; ms < 2; ms++)
        #pragma unroll
        for (int ns = 0; ns < 4; ns++)
            #pragma unroll
            for (int r = 0; r < 4; r++) {
                int row = m0 + 32 * w + ms * 16 + quad * 4 + r;
                int col = h * DH_ + ns * 16 + l15;
                Qb[(size_t)row * D_ + col] = bfc(acc[0][ms][ns][r] * qs);
                Kb[(size_t)row * D_ + col] = bfc(acc[1][ms][ns][r]);
            }
    #pragma unroll
    for (int ms = 0; ms < 2; ms++)
        #pragma unroll
        for (int ns = 0; ns < 4; ns++)
            #pragma unroll
            for (int r = 0; r < 4; r++) {
                int sl = 32 * w + ms * 16 + quad * 4 + r;
                int e  = ns * 16 + l15;
                XsT[e * 136 + sl] = bfc(acc[2][ms][ns][r]);
            }
    __syncthreads();
    #pragma unroll
    for (int i = 0; i < 4; i++) {
        int v = tid + 256 * i;
        int e = v >> 4, s0 = (v & 15) * 8;
        svec8 d = *(const svec8*)(XsT + e * 136 + s0);
        *(svec8*)(Vg + (size_t)(h * DH_ + e) * BS_ + m0 + s0) = d;
    }
}

// ---------------- causal flash attention (R15: QBLK=128, LDS reads amortized 2x) ----
// R14 calibration: attn is LDS-pipe-bound (~81 of 114.7 us: 16 b128 reads/wave-iter,
// 4 waves re-reading IDENTICAL K/V fragments). R15: each wave owns 32 q rows (two
// B-fragments aqA/aqB; halves A = rows [q0,q0+64), B = [q0+64,q0+128)). Every ka/bv
// LDS read now feeds TWO MFMAs -> LDS traffic and barriers per score halve.
//
// Grid: 768 blocks (32 q-tiles x 24 bh), all co-resident at 3/CU. Balance is exact
// via closed-form triples: CU slot c = fid%256, t = c&31 gets qt' = {t, (t+16)%32,
// t<16 ? 30-2t : 63-2t} across rounds fid/256 -- sums 46/47 (98/100 key-tiles per
// CU). Bijective over (qt',h,b): hb = (fid>>8)*8 + (c>>5).
//
// Last tile (kt == qt2): half A is fully masked (-INF -> p=0) instead of branched
// out -- uniform code, ~3% waste. Diagonal masks: A at kt==qt2-1, B at kt==qt2.
__global__ __launch_bounds__(256, 3) void attn(
    const ushort_t* __restrict__ Qb, const ushort_t* __restrict__ Kb,
    const ushort_t* __restrict__ Vg, float* __restrict__ Out)
{
    const int fid = blockIdx.x;                 // 0..767
    const int c   = fid & 255;
    const int rnd = fid >> 8;                   // 0..2
    const int t   = c & 31;
    const int u   = c >> 5;
    const int qtp = (rnd == 0) ? t : (rnd == 1) ? ((t + 16) & 31)
                                                : (t < 16 ? 30 - 2 * t : 63 - 2 * t);
    const int hb  = rnd * 8 + u;                // 0..23
    const int h   = hb % H_;
    const int b   = hb / H_;
    const int q0  = qtp * 128;
    const int qt2 = 2 * qtp + 1;                // last key-tile index

    const int tid  = threadIdx.x;
    const int w    = tid >> 6;
    const int lane = tid & 63;
    const int quad = lane >> 4;
    const int l15  = lane & 15;

    __shared__ ushort_t Ks[64 * 72];       // K tile, ROW-PERMUTED: LDS row m = key pi(m)
    __shared__ ushort_t Vt[64 * 72];       // V^T tile [e][key]

    const size_t hboff = (size_t)b * S_ * D_ + (size_t)h * DH_;
    const ushort_t* Vh = Vg + (size_t)h * DH_ * BS_ + (size_t)b * S_;

    const int sr = tid >> 3;          // staging row 0..31 (+32)
    const int sc = (tid & 7) * 8;
    // pinv(k): LDS row where key k lives.  m4=k5, m3=k4, m2=k3, m5=k2, m1m0=k1k0
    const int pr0 = (((sr      >> 2) & 1) << 5) | (((sr      >> 5) & 1) << 4) |
                    (((sr      >> 4) & 1) << 3) | (((sr      >> 3) & 1) << 2) | (sr & 3);
    const int sr1 = sr + 32;
    const int pr1 = (((sr1 >> 2) & 1) << 5) | (((sr1 >> 5) & 1) << 4) |
                    (((sr1 >> 4) & 1) << 3) | (((sr1 >> 3) & 1) << 2) | (sr1 & 3);

    // Q fragments for both halves (pre-scaled to log2 domain in qkv_proj)
    svec8 aqA[2], aqB[2];
    {
        const ushort_t* qra = Qb + hboff + (size_t)(q0 + 16 * w + l15) * D_;
        aqA[0] = *(const svec8*)(qra + quad * 8);
        aqA[1] = *(const svec8*)(qra + 32 + quad * 8);
        const ushort_t* qrb = qra + (size_t)64 * D_;
        aqB[0] = *(const svec8*)(qrb + quad * 8);
        aqB[1] = *(const svec8*)(qrb + 32 + quad * 8);
    }

    float miA = -INFINITY, miB = -INFINITY;
    float lsA = 0.f, lsB = 0.f;
    fvec4 accA[4], accB[4];
    #pragma unroll
    for (int n = 0; n < 4; n++) {
        accA[n] = (fvec4){0.f, 0.f, 0.f, 0.f};
        accB[n] = (fvec4){0.f, 0.f, 0.f, 0.f};
    }

    const ushort_t* kp = Kb + hboff + (size_t)sr * D_ + sc;
    const ushort_t* vp = Vh + (size_t)sr * BS_ + sc;

    // prologue: stage tile 0
    svec8 kd[2], vd[2];
    kd[0] = *(const svec8*)(kp);
    kd[1] = *(const svec8*)(kp + (size_t)32 * D_);
    vd[0] = *(const svec8*)(vp);
    vd[1] = *(const svec8*)(vp + (size_t)32 * BS_);
    kp += (size_t)64 * D_;
    vp += 64;
    *(svec8*)(Ks + pr0 * 72 + sc) = kd[0];
    *(svec8*)(Ks + pr1 * 72 + sc) = kd[1];
    *(svec8*)(Vt + sr  * 72 + sc) = vd[0];
    *(svec8*)(Vt + sr1 * 72 + sc) = vd[1];

    for (int kt = 0; kt <= qt2; ++kt) {
        __syncthreads();   // staged tile kt visible to all waves

        if (kt < qt2) {
            kd[0] = *(const svec8*)(kp);
            kd[1] = *(const svec8*)(kp + (size_t)32 * D_);
            vd[0] = *(const svec8*)(vp);
            vd[1] = *(const svec8*)(vp + (size_t)32 * BS_);
            kp += (size_t)64 * D_;
            vp += 64;
        }

        // S^T = K_perm Q^T for both halves; each ka read feeds 2 MFMAs
        fvec4 stA[4], stB[4];
        #pragma unroll
        for (int n = 0; n < 4; n++) {
            stA[n] = (fvec4){0.f, 0.f, 0.f, 0.f};
            stB[n] = (fvec4){0.f, 0.f, 0.f, 0.f};
        }
        #pragma unroll
        for (int ks = 0; ks < 2; ks++)
            #pragma unroll
            for (int n = 0; n < 4; n++) {
                svec8 ka = *(const svec8*)(Ks + (n * 16 + l15) * 72 + ks * 32 + quad * 8);
                stA[n] = mfma16(ka, aqA[ks], stA[n]);
                stB[n] = mfma16(ka, aqB[ks], stB[n]);
            }

        // masks: A diagonal at kt==qt2-1; at kt==qt2 A is fully masked, B diagonal
        if (kt == qt2 - 1) {
            #pragma unroll
            for (int n = 0; n < 4; n++)
                #pragma unroll
                for (int r = 0; r < 4; r++) {
                    int key = (n & 1) * 32 + quad * 8 + (n >> 1) * 4 + r;
                    int row = 16 * w + l15;
                    if (key > row) stA[n][r] = -INFINITY;
                }
        }
        if (kt == qt2) {
            #pragma unroll
            for (int n = 0; n < 4; n++)
                #pragma unroll
                for (int r = 0; r < 4; r++) {
                    stA[n][r] = -INFINITY;
                    int key = (n & 1) * 32 + quad * 8 + (n >> 1) * 4 + r;
                    int row = 16 * w + l15;
                    if (key > row) stB[n][r] = -INFINITY;
                }
        }

        // per-row maxes (both halves), butterfly across quads
        float mxA, mxB;
        {
            float m1 = fmaxf(fmaxf(stA[0][0], stA[0][1]), stA[0][2]);
            m1 = fmaxf(fmaxf(m1, stA[0][3]), stA[1][0]);
            m1 = fmaxf(fmaxf(m1, stA[1][1]), stA[1][2]);
            m1 = fmaxf(m1, stA[1][3]);
            float m2 = fmaxf(fmaxf(stA[2][0], stA[2][1]), stA[2][2]);
            m2 = fmaxf(fmaxf(m2, stA[2][3]), stA[3][0]);
            m2 = fmaxf(fmaxf(m2, stA[3][1]), stA[3][2]);
            m2 = fmaxf(m2, stA[3][3]);
            mxA = fmaxf(m1, m2);
            mxA = fmaxf(mxA, __shfl_xor(mxA, 16));
            mxA = fmaxf(mxA, __shfl_xor(mxA, 32));
        }
        {
            float m1 = fmaxf(fmaxf(stB[0][0], stB[0][1]), stB[0][2]);
            m1 = fmaxf(fmaxf(m1, stB[0][3]), stB[1][0]);
            m1 = fmaxf(fmaxf(m1, stB[1][1]), stB[1][2]);
            m1 = fmaxf(m1, stB[1][3]);
            float m2 = fmaxf(fmaxf(stB[2][0], stB[2][1]), stB[2][2]);
            m2 = fmaxf(fmaxf(m2, stB[2][3]), stB[3][0]);
            m2 = fmaxf(fmaxf(m2, stB[3][1]), stB[3][2]);
            m2 = fmaxf(m2, stB[3][3]);
            mxB = fmaxf(m1, m2);
            mxB = fmaxf(mxB, __shfl_xor(mxB, 16));
            mxB = fmaxf(mxB, __shfl_xor(mxB, 32));
        }

        // skip-rescale (alpha==1 everywhere unless some row's max grew; exact)
        if (__any((mxA > miA) || (mxB > miB))) {
            float mnA = fmaxf(miA, mxA), mnB = fmaxf(miB, mxB);
            float aA = exp2f(miA - mnA), aB = exp2f(miB - mnB);
            miA = mnA; miB = mnB;
            lsA *= aA; lsB *= aB;
            #pragma unroll
            for (int r = 0; r < 4; r++) {
                float arA = __shfl(aA, quad * 16 + quad * 4 + r);
                float arB = __shfl(aB, quad * 16 + quad * 4 + r);
                #pragma unroll
                for (int n = 0; n < 4; n++) {
                    accA[n][r] *= arA;
                    accB[n][r] *= arB;
                }
            }
        }

        // p = exp2(st - m); pack into PV A-fragments (cvt_pk); accumulate denoms
        svec8 apA0, apA1, apB0, apB1;
        {
            ivec4 ai0, ai1;
            float ps[4];
            #pragma unroll
            for (int n = 0; n < 4; n++) {
                float p0 = exp2f(stA[n][0] - miA);
                float p1 = exp2f(stA[n][1] - miA);
                float p2 = exp2f(stA[n][2] - miA);
                float p3 = exp2f(stA[n][3] - miA);
                ps[n] = (p0 + p1) + (p2 + p3);
                unsigned d0 = cvt_pk_bf16(p0, p1);
                unsigned d1 = cvt_pk_bf16(p2, p3);
                if (n == 0)      { ai0[0] = (int)d0; ai0[1] = (int)d1; }
                else if (n == 1) { ai1[0] = (int)d0; ai1[1] = (int)d1; }
                else if (n == 2) { ai0[2] = (int)d0; ai0[3] = (int)d1; }
                else             { ai1[2] = (int)d0; ai1[3] = (int)d1; }
            }
            lsA += (ps[0] + ps[2]) + (ps[1] + ps[3]);
            apA0 = __builtin_bit_cast(svec8, ai0);
            apA1 = __builtin_bit_cast(svec8, ai1);
        }
        {
            ivec4 ai0, ai1;
            float ps[4];
            #pragma unroll
            for (int n = 0; n < 4; n++) {
                float p0 = exp2f(stB[n][0] - miB);
                float p1 = exp2f(stB[n][1] - miB);
                float p2 = exp2f(stB[n][2] - miB);
                float p3 = exp2f(stB[n][3] - miB);
                ps[n] = (p0 + p1) + (p2 + p3);
                unsigned d0 = cvt_pk_bf16(p0, p1);
                unsigned d1 = cvt_pk_bf16(p2, p3);
                if (n == 0)      { ai0[0] = (int)d0; ai0[1] = (int)d1; }
                else if (n == 1) { ai1[0] = (int)d0; ai1[1] = (int)d1; }
                else if (n == 2) { ai0[2] = (int)d0; ai0[3] = (int)d1; }
                else             { ai1[2] = (int)d0; ai1[3] = (int)d1; }
            }
            lsB += (ps[0] + ps[2]) + (ps[1] + ps[3]);
            apB0 = __builtin_bit_cast(svec8, ai0);
            apB1 = __builtin_bit_cast(svec8, ai1);
        }

        // O += P V; each bv read feeds 2 MFMAs
        #pragma unroll
        for (int ks = 0; ks < 2; ks++) {
            svec8 apa = ks ? apA1 : apA0;
            svec8 apb = ks ? apB1 : apB0;
            #pragma unroll
            for (int n = 0; n < 4; n++) {
                svec8 bv = *(const svec8*)(Vt + (n * 16 + l15) * 72 + ks * 32 + quad * 8);
                accA[n] = mfma16(apa, bv, accA[n]);
                accB[n] = mfma16(apb, bv, accB[n]);
            }
        }

        __syncthreads();   // all waves done reading tile kt

        if (kt < qt2) {
            *(svec8*)(Ks + pr0 * 72 + sc) = kd[0];
            *(svec8*)(Ks + pr1 * 72 + sc) = kd[1];
            *(svec8*)(Vt + sr  * 72 + sc) = vd[0];
            *(svec8*)(Vt + sr1 * 72 + sc) = vd[1];
        }
    }

    // epilogue: denominators per half (2 shuffles each), divide, store both halves
    float lsumA = lsA;
    lsumA += __shfl_xor(lsumA, 16);
    lsumA += __shfl_xor(lsumA, 32);
    float lsumB = lsB;
    lsumB += __shfl_xor(lsumB, 16);
    lsumB += __shfl_xor(lsumB, 32);
    #pragma unroll
    for (int r = 0; r < 4; r++) {
        float liA = __shfl(lsumA, quad * 16 + quad * 4 + r);
        float liB = __shfl(lsumB, quad * 16 + quad * 4 + r);
        int rowA = q0 + 16 * w + quad * 4 + r;
        #pragma unroll
        for (int n = 0; n < 4; n++) {
            int col = h * DH_ + n * 16 + l15;
            Out[((size_t)b * S_ + rowA) * D_ + col]      = accA[n][r] / liA;
            Out[((size_t)b * S_ + rowA + 64) * D_ + col] = accB[n][r] / liB;
        }
    }
}

extern "C" void kernel_launch(void* const* d_in, const int* in_sizes, int n_in,
                              void* d_out, int out_size, void* d_ws, size_t ws_size,
                              hipStream_t stream)
{
    const float* X  = (const float*)d_in[0];
    const float* Wq = (const float*)d_in[1];
    const float* Wk = (const float*)d_in[2];
    const float* Wv = (const float*)d_in[3];

    ushort_t* Qb = (ushort_t*)d_ws;                      // 8192*768 bf16 (pre-scaled)
    ushort_t* Kb = Qb + (size_t)BS_ * D_;                // 8192*768 bf16
    ushort_t* Vg = Kb + (size_t)BS_ * D_;                // [768][8192] bf16 transposed

    // scratch inside d_out (25.2 MB fp32 buffer): attn fully overwrites it at the
    // end, and prep/qkv/attn serialize on one stream -> safe.
    ushort_t* Xb  = (ushort_t*)d_out;                    // [8192][768] bf16 (12.6 MB)
    ushort_t* Wsz = Xb + (size_t)BS_ * D_;               // [h][kt][wt][4096] (3.5 MB)
    float* Out = (float*)d_out;

    prep<<<dim3(3072 + 432), dim3(256), 0, stream>>>(X, Wq, Wk, Wv, Xb, Wsz);
    qkv_proj<<<dim3(64, H_), dim3(256), 0, stream>>>(Xb, Wsz, Qb, Kb, Vg);
    attn<<<dim3(768), dim3(256), 0, stream>>>(Qb, Kb, Vg, Out);
}